// Round 11
// baseline (116.497 us; speedup 1.0000x reference)
//
#include <hip/hip_runtime.h>
#include <math.h>

#define BB 32
#define CC 768
#define HID 96
#define NPIX 1024
#define KSEL 256
#define BN_EPS_F 1e-5f

typedef __bf16 bf16x8 __attribute__((ext_vector_type(8)));
typedef float f32x4 __attribute__((ext_vector_type(4)));

__device__ __forceinline__ unsigned short f2bf(float f) {
    unsigned u = __float_as_uint(f);
    return (unsigned short)((u + 0x7FFFu + ((u >> 16) & 1u)) >> 16);  // RNE
}
__device__ __forceinline__ unsigned pack2(float lo, float hi) {
    return (unsigned)f2bf(lo) | ((unsigned)f2bf(hi) << 16);
}

// ---------------------------------------------------------------------------
// K0: prep — w1 f32 -> bf16 [96][768]; BN scale/shift [96]. grid 73 x 256.
// ---------------------------------------------------------------------------
__global__ __launch_bounds__(256) void k0_prep(
    const float* __restrict__ w1, const float* __restrict__ gamma,
    const float* __restrict__ beta, const float* __restrict__ mean,
    const float* __restrict__ var,
    unsigned short* __restrict__ w1b, float* __restrict__ scale,
    float* __restrict__ shift)
{
    int t = threadIdx.x, bk = blockIdx.x;
    if (bk < 72) {
        int idx = (bk * 256 + t) * 4;
        float4 v = *reinterpret_cast<const float4*>(w1 + idx);
        uint2 o;
        o.x = pack2(v.x, v.y);
        o.y = pack2(v.z, v.w);
        *reinterpret_cast<uint2*>(w1b + idx) = o;
    } else if (t < HID) {
        float sc = gamma[t] * rsqrtf(var[t] + BN_EPS_F);
        scale[t] = sc;
        shift[t] = beta[t] - mean[t] * sc;
    }
}

// ---------------------------------------------------------------------------
// KP: transpose+pack x[b][c][n] f32 -> xt[b][n][c] bf16.
// grid (24 c-tiles of 32, 32 b) = 768 blocks, 256 thr. Tile 32c x 1024n.
// READ: full 4KB rows, fully sequential (the clean DRAM/L3 pattern).
// LDS: uint Lu[32][517] (odd stride -> conflict-free both phases).
// WRITE: 64B per 4-lane group, aligned.
// ---------------------------------------------------------------------------
__global__ __launch_bounds__(256) void kP_transpose(
    const float* __restrict__ x, unsigned short* __restrict__ xt)
{
    __shared__ unsigned Lu[32 * 517];   // row r at Lu[r*517 .. +512)

    const int t = threadIdx.x;
    const int c0 = blockIdx.x * 32, b = blockIdx.y;

    // ---- read+pack phase: 4 passes of 8 rows ----
#pragma unroll
    for (int p = 0; p < 4; ++p) {
        int r = p * 8 + (t >> 5);            // 0..31
        int seg = t & 31;                    // 32 segs x 128B per row
        const float* src = x + ((size_t)b * CC + c0 + r) * NPIX + seg * 32;
        unsigned* dst = &Lu[r * 517 + seg * 16];
#pragma unroll
        for (int j = 0; j < 8; ++j) {
            float4 v = *reinterpret_cast<const float4*>(src + 4 * j);
            dst[2 * j]     = pack2(v.x, v.y);
            dst[2 * j + 1] = pack2(v.z, v.w);
        }
    }
    __syncthreads();

    // ---- write phase: 16 iters; 4 lanes per n-row (64B contiguous) ----
    const int l4 = t & 3;                    // c-subchunk (8 c)
    const int nq = t >> 2;                   // 0..63
#pragma unroll 4
    for (int it = 0; it < 16; ++it) {
        int n = it * 64 + nq;
        unsigned ou[4];
#pragma unroll
        for (int i2 = 0; i2 < 4; ++i2) {
            int cl0 = l4 * 8 + 2 * i2;
            unsigned a = Lu[cl0 * 517 + (n >> 1)];
            unsigned c = Lu[(cl0 + 1) * 517 + (n >> 1)];
            unsigned sa = (n & 1) ? (a >> 16) : (a & 0xffffu);
            unsigned sc = (n & 1) ? (c >> 16) : (c & 0xffffu);
            ou[i2] = sa | (sc << 16);
        }
        uint4 o4 = {ou[0], ou[1], ou[2], ou[3]};
        *reinterpret_cast<uint4*>(
            xt + ((size_t)b * NPIX + n) * CC + c0 + l4 * 8) = o4;
    }
}

// ---------------------------------------------------------------------------
// K1 v8: bf16 MFMA GEMM from TRANSPOSED xt. H[o,n] = sum_c w1[o,c]*xt[n][c].
// grid (16 n-tiles of 64, 32 b) = 512 blocks, 512 thr = 8 waves.
// Wave (wo,wn) = 48o x 16n. B-fragment = ONE dwordx4 (lane's k-run is
// contiguous in xt) -> zero pack VALU, clean 16B requests.
// W staged per K-half in LDS (74.5 KB, stride 388). 3 barriers total.
// ---------------------------------------------------------------------------
__global__ __launch_bounds__(512) void k1_gemm_mfma(
    const unsigned short* __restrict__ xt, const unsigned short* __restrict__ w1b,
    const float* __restrict__ scale, const float* __restrict__ shift,
    float* __restrict__ h_out)
{
    constexpr int WSTR = 388;
    __shared__ unsigned short Ws[96 * WSTR];   // 74.5 KB, one K-half
    __shared__ float sc_s[HID], sh_s[HID];

    const int t = threadIdx.x;
    const int b = blockIdx.y;
    const int n0 = blockIdx.x * 64;
    const int wave = t >> 6, lane = t & 63;
    const int lm = lane & 15, g = lane >> 4;
    const int wo = wave >> 2, wn = wave & 3;
    const int n = n0 + wn * 16 + lm;

    if (t < HID) { sc_s[t] = scale[t]; sh_s[t] = shift[t]; }

    f32x4 acc[3];
#pragma unroll
    for (int mt = 0; mt < 3; ++mt) acc[mt] = (f32x4){0.f, 0.f, 0.f, 0.f};

    const unsigned short* xrow = xt + ((size_t)b * NPIX + n) * CC + g * 8;

#define STAGE_W(half) do {                                                    \
    _Pragma("unroll")                                                         \
    for (int i = 0; i < 9; ++i) {                                             \
        int idx = t + i * 512;                     /* 0..4607 */              \
        int row = idx / 48, k8 = (idx % 48) * 8;                              \
        uint4 wv = *reinterpret_cast<const uint4*>(                           \
            w1b + (size_t)row * CC + (half) * 384 + k8);                      \
        *reinterpret_cast<uint4*>(&Ws[row * WSTR + k8]) = wv;                 \
    } } while (0)

#define LOADB(dst, ck) do {                                                   \
    dst = *reinterpret_cast<const uint4*>(xrow + (size_t)(ck) * 32);          \
    } while (0)

#define DOCHUNK(ckk, bu) do {                                                 \
    bf16x8 bfr = __builtin_bit_cast(bf16x8, bu);                              \
    _Pragma("unroll")                                                         \
    for (int mt = 0; mt < 3; ++mt) {                                          \
        uint4 au = *reinterpret_cast<const uint4*>(                           \
            &Ws[(wo * 48 + mt * 16 + lm) * WSTR + (ckk) * 32 + g * 8]);       \
        acc[mt] = __builtin_amdgcn_mfma_f32_16x16x32_bf16(                    \
            __builtin_bit_cast(bf16x8, au), bfr, acc[mt], 0, 0, 0);           \
    } } while (0)

#define STEP(ck, SLOT) do {                                                   \
    uint4 bu = SLOT;                                                          \
    if ((ck) + 4 < 24) LOADB(SLOT, (ck) + 4);                                 \
    DOCHUNK((ck) % 12, bu);                                                   \
    } while (0)

    uint4 x0, x1, x2, x3;

    STAGE_W(0);
    LOADB(x0, 0); LOADB(x1, 1); LOADB(x2, 2); LOADB(x3, 3);
    __syncthreads();

    STEP(0, x0);  STEP(1, x1);  STEP(2, x2);  STEP(3, x3);
    STEP(4, x0);  STEP(5, x1);  STEP(6, x2);  STEP(7, x3);
    STEP(8, x0);  STEP(9, x1);  STEP(10, x2); STEP(11, x3);
    __syncthreads();
    STAGE_W(1);
    __syncthreads();
    STEP(12, x0); STEP(13, x1); STEP(14, x2); STEP(15, x3);
    STEP(16, x0); STEP(17, x1); STEP(18, x2); STEP(19, x3);
    STEP(20, x0); STEP(21, x1); STEP(22, x2); STEP(23, x3);

    // epilogue: C/D col = lm (n), row = g*4 + r (o); BN + ReLU
#pragma unroll
    for (int mt = 0; mt < 3; ++mt) {
#pragma unroll
        for (int r = 0; r < 4; ++r) {
            int o = wo * 48 + mt * 16 + g * 4 + r;
            float v = fmaxf(acc[mt][r] * sc_s[o] + sh_s[o], 0.f);
            h_out[((size_t)b * HID + o) * NPIX + n] = v;
        }
    }
#undef STAGE_W
#undef LOADB
#undef DOCHUNK
#undef STEP
}

// ---------------------------------------------------------------------------
// K2: 3x3 conv HID->1, SAME. grid (8 y-tiles of 4 rows, 32 b) = 256 blocks,
// 128 thr (1 px/thread). 16-channel LDS chunks with row halo.
// ---------------------------------------------------------------------------
__global__ __launch_bounds__(128) void k2_conv3x3(
    const float* __restrict__ h_in, const float* __restrict__ w2,
    const float* __restrict__ b2, float* __restrict__ score_out)
{
    __shared__ float hs[16][6][40];   // interior cols 4..35; halo cols 3 and 36
    __shared__ float w2s[HID * 9];

    const int t = threadIdx.x;
    const int ytile = blockIdx.x, b = blockIdx.y;
    const int y = t >> 5, xx = t & 31;
    const int Y = ytile * 4 + y;

    for (int i = t; i < HID * 9; i += 128) w2s[i] = w2[i];

    const float* hb = h_in + (size_t)b * HID * NPIX;
    float acc = 0.f;

    for (int c0 = 0; c0 < HID; c0 += 16) {
        __syncthreads();
        for (int i = t; i < 192; i += 128) {  // zero halo cols (3 and 36)
            int ch = i / 12, rr = (i % 12) >> 1, col = (i & 1) ? 36 : 3;
            hs[ch][rr][col] = 0.f;
        }
#pragma unroll
        for (int i = 0; i < 6; ++i) {
            int idx = t + i * 128;               // 0..767 float4 slots
            int ch = idx / 48, rem = idx % 48;
            int rr = rem >> 3, qq = rem & 7;
            int gy = ytile * 4 - 1 + rr;
            float4 v = (gy >= 0 && gy < 32)
                ? *reinterpret_cast<const float4*>(
                      hb + (size_t)(c0 + ch) * NPIX + gy * 32 + qq * 4)
                : (float4){0.f, 0.f, 0.f, 0.f};
            *reinterpret_cast<float4*>(&hs[ch][rr][4 + qq * 4]) = v;
        }
        __syncthreads();
#pragma unroll
        for (int ch = 0; ch < 16; ++ch) {
            float s = 0.f;
#pragma unroll
            for (int ky = 0; ky < 3; ++ky)
#pragma unroll
                for (int kx = 0; kx < 3; ++kx)
                    s += hs[ch][y + ky][3 + xx + kx] * w2s[(c0 + ch) * 9 + ky * 3 + kx];
            acc += s;
        }
    }
    score_out[b * NPIX + Y * 32 + xx] = acc + b2[0];
}

// ---------------------------------------------------------------------------
// K3: exact top-256 (radix select, first-index tie-break) + softmax ->
// dense weight[1024]. grid 32, 256 thr; elements register-resident (4/thr).
// ---------------------------------------------------------------------------
__global__ __launch_bounds__(256) void k3_topk_softmax(
    const float* __restrict__ score, float* __restrict__ weight)
{
    __shared__ unsigned hist[256];
    __shared__ unsigned wtot[4];
    __shared__ unsigned pcnt16[16];
    __shared__ float redf[4];
    __shared__ unsigned sh_bin, sh_rem;

    const int t = threadIdx.x, b = blockIdx.x;
    const int lane = t & 63, wv = t >> 6;

    float fvals[4];
    unsigned uvals[4];
#pragma unroll
    for (int i = 0; i < 4; ++i) {
        float f = score[b * NPIX + t + 256 * i];
        fvals[i] = f;
        unsigned u = __float_as_uint(f);
        uvals[i] = (u & 0x80000000u) ? ~u : (u | 0x80000000u);
    }

    unsigned prefix = 0, rem = KSEL;
    for (int p = 3; p >= 0; --p) {
        hist[t] = 0;
        __syncthreads();
        const int sh_hi = (p + 1) * 8;
#pragma unroll
        for (int i = 0; i < 4; ++i) {
            unsigned u = uvals[i];
            bool match = (p == 3) || ((u >> sh_hi) == (prefix >> sh_hi));
            if (match) atomicAdd(&hist[(u >> (p * 8)) & 0xffu], 1u);
        }
        __syncthreads();
        unsigned own = hist[t];
        unsigned val = own;
#pragma unroll
        for (int off = 1; off <= 32; off <<= 1) {
            unsigned o2 = __shfl_down(val, off);
            if (lane + off < 64) val += o2;
        }
        if (lane == 0) wtot[wv] = val;
        __syncthreads();
        unsigned suff = val;
        for (int w = wv + 1; w < 4; ++w) suff += wtot[w];
        unsigned nexts = suff - own;        // count with bin > t
        if (suff >= rem && nexts < rem) { sh_bin = (unsigned)t; sh_rem = rem - nexts; }
        __syncthreads();
        prefix |= (sh_bin << (p * 8));
        rem = sh_rem;
        __syncthreads();
    }
    const unsigned T = prefix, need = rem;

    float m = -INFINITY;
#pragma unroll
    for (int i = 0; i < 4; ++i) m = fmaxf(m, fvals[i]);
#pragma unroll
    for (int off = 32; off >= 1; off >>= 1) m = fmaxf(m, __shfl_xor(m, off));
    if (lane == 0) redf[wv] = m;
    __syncthreads();
    m = fmaxf(fmaxf(redf[0], redf[1]), fmaxf(redf[2], redf[3]));

    unsigned lp[4]; bool eqf[4], gtf[4];
    unsigned long long lmask = (1ULL << lane) - 1ULL;
#pragma unroll
    for (int i = 0; i < 4; ++i) {
        bool eq = (uvals[i] == T);
        eqf[i] = eq; gtf[i] = (uvals[i] > T);
        unsigned long long mk = __ballot(eq);
        lp[i] = (unsigned)__popcll(mk & lmask);
        if (lane == 0) pcnt16[i * 4 + wv] = (unsigned)__popcll(mk);
    }
    __syncthreads();
    unsigned cum = 0, baseArr[4];
#pragma unroll
    for (int ii = 0; ii < 4; ++ii) {
        unsigned b0 = cum;
        for (int w = 0; w < wv; ++w) b0 += pcnt16[ii * 4 + w];
        baseArr[ii] = b0;
        for (int w = 0; w < 4; ++w) cum += pcnt16[ii * 4 + w];
    }
    float evals[4], sumExp = 0.f;
#pragma unroll
    for (int i = 0; i < 4; ++i) {
        bool sel = gtf[i] || (eqf[i] && (baseArr[i] + lp[i]) < need);
        float e = sel ? expf(fvals[i] - m) : 0.f;
        evals[i] = e;
        sumExp += e;
    }
#pragma unroll
    for (int off = 32; off >= 1; off >>= 1) sumExp += __shfl_xor(sumExp, off);
    if (lane == 0) redf[wv] = sumExp;
    __syncthreads();
    float inv = 1.0f / (redf[0] + redf[1] + redf[2] + redf[3]);
#pragma unroll
    for (int i = 0; i < 4; ++i)
        weight[b * NPIX + i * 256 + t] = evals[i] * inv;
}

// ---------------------------------------------------------------------------
// K4: v[b,c] = sum_n x[b,c,n]*weight[b,n]. grid 32*192, 4 waves, 1 c/wave.
// ---------------------------------------------------------------------------
__global__ __launch_bounds__(256) void k4_weighted_sum(
    const float* __restrict__ x, const float* __restrict__ weight,
    float* __restrict__ v)
{
    __shared__ float wsm[NPIX];
    const int t = threadIdx.x;
    const int b = blockIdx.x / 192, cg = blockIdx.x % 192;

    *reinterpret_cast<float4*>(&wsm[t * 4]) =
        *reinterpret_cast<const float4*>(&weight[b * NPIX + t * 4]);
    __syncthreads();

    const int lane = t & 63, wvv = t >> 6;
    const int c = cg * 4 + wvv;
    const float* xr = x + ((size_t)b * CC + c) * NPIX;

    float acc = 0.f;
#pragma unroll
    for (int j = 0; j < 4; ++j) {
        int off = j * 256 + lane * 4;
        float4 xv = *reinterpret_cast<const float4*>(xr + off);
        float4 wv4 = *reinterpret_cast<const float4*>(&wsm[off]);
        acc += xv.x * wv4.x + xv.y * wv4.y + xv.z * wv4.z + xv.w * wv4.w;
    }
#pragma unroll
    for (int off = 32; off >= 1; off >>= 1) acc += __shfl_xor(acc, off);
    if (lane == 0) v[(size_t)b * CC + c] = acc;
}

// ---------------------------------------------------------------------------
extern "C" void kernel_launch(void* const* d_in, const int* in_sizes, int n_in,
                              void* d_out, int out_size, void* d_ws, size_t ws_size,
                              hipStream_t stream)
{
    const float* x     = (const float*)d_in[0];
    const float* w1    = (const float*)d_in[1];
    const float* gamma = (const float*)d_in[2];
    const float* beta  = (const float*)d_in[3];
    const float* mean  = (const float*)d_in[4];
    const float* var   = (const float*)d_in[5];
    const float* w2    = (const float*)d_in[6];
    const float* b2    = (const float*)d_in[7];

    float* out   = (float*)d_out;
    float* vout  = out;                  // [32,768]
    float* score = out + BB * CC;        // [32,1024]

    unsigned short* xt = (unsigned short*)d_ws;                 // 32*1024*768 bf16
    float* h      = (float*)(xt + (size_t)BB * NPIX * CC);      // 32*96*1024 f32
    float* weight = h + (size_t)BB * HID * NPIX;                // 32*1024 f32
    unsigned short* w1b = (unsigned short*)(weight + BB * NPIX);// 96*768 bf16
    float* scale  = (float*)(w1b + HID * CC);                   // 96
    float* shift  = scale + HID;                                // 96

    k0_prep<<<73, 256, 0, stream>>>(w1, gamma, beta, mean, var, w1b, scale, shift);
    kP_transpose<<<dim3(24, BB), 256, 0, stream>>>(x, xt);
    k1_gemm_mfma<<<dim3(16, BB), 512, 0, stream>>>(xt, w1b, scale, shift, h);
    k2_conv3x3<<<dim3(8, BB), 128, 0, stream>>>(h, w2, b2, score);
    k3_topk_softmax<<<BB, 256, 0, stream>>>(score, weight);
    k4_weighted_sum<<<BB * (CC / 4), 256, 0, stream>>>(x, weight, vout);
}

// Round 12
// 77.237 us; speedup vs baseline: 1.5083x; 1.5083x over previous
//
#include <hip/hip_runtime.h>
#include <math.h>

#define BB 32
#define CC 768
#define HID 96
#define NPIX 1024
#define KSEL 256
#define BN_EPS_F 1e-5f

typedef __bf16 bf16x8 __attribute__((ext_vector_type(8)));
typedef float f32x4 __attribute__((ext_vector_type(4)));

typedef const __attribute__((address_space(1))) void* gas_p;
typedef __attribute__((address_space(3))) void* las_p;

__device__ __forceinline__ unsigned short f2bf(float f) {
    unsigned u = __float_as_uint(f);
    return (unsigned short)((u + 0x7FFFu + ((u >> 16) & 1u)) >> 16);  // RNE
}
__device__ __forceinline__ unsigned pack2(float lo, float hi) {
    return (unsigned)f2bf(lo) | ((unsigned)f2bf(hi) << 16);
}

// ---------------------------------------------------------------------------
// K0: prep — w1 f32 -> bf16 [96][768]; BN scale/shift [96]. grid 73 x 256.
// ---------------------------------------------------------------------------
__global__ __launch_bounds__(256) void k0_prep(
    const float* __restrict__ w1, const float* __restrict__ gamma,
    const float* __restrict__ beta, const float* __restrict__ mean,
    const float* __restrict__ var,
    unsigned short* __restrict__ w1b, float* __restrict__ scale,
    float* __restrict__ shift)
{
    int t = threadIdx.x, bk = blockIdx.x;
    if (bk < 72) {
        int idx = (bk * 256 + t) * 4;
        float4 v = *reinterpret_cast<const float4*>(w1 + idx);
        uint2 o;
        o.x = pack2(v.x, v.y);
        o.y = pack2(v.z, v.w);
        *reinterpret_cast<uint2*>(w1b + idx) = o;
    } else if (t < HID) {
        float sc = gamma[t] * rsqrtf(var[t] + BN_EPS_F);
        scale[t] = sc;
        shift[t] = beta[t] - mean[t] * sc;
    }
}

// ---------------------------------------------------------------------------
// K1 v10: bf16 MFMA GEMM, X staged via ASYNC global_load_lds (width 16).
// grid (16 n-tiles of 64, 32 b) = 512 blocks, 512 thr = 8 waves, 2 blk/CU.
// Per chunk (64c x 64n f32 = 16KB): the ENTIRE next tile is issued async
// BEFORE compute -> ~32KB/CU in flight at each barrier drain (reg-staging
// kept <1KB; needed ~9KB). LDS is linear (gload_lds requirement); bank
// conflicts avoided by PRE-SWIZZLED GLOBAL SOURCE: slot = n ^ ((c>>2)&3)*8
// (<=2-way on staging and on fragment reads, verified per-instruction).
// W: reg-staged dbuf LDS [96][68] (v4's proven conflict-light path).
// f32->bf16 pack on consumption (8 b32 reads + 4 pack2 per half).
// ---------------------------------------------------------------------------
__global__ __launch_bounds__(512, 4) void k1_gemm_mfma(
    const float* __restrict__ x, const unsigned short* __restrict__ w1b,
    const float* __restrict__ scale, const float* __restrict__ shift,
    float* __restrict__ h_out)
{
    __shared__ float Xs[2][64 * 64];            // linear [c][n], swizzled src
    __shared__ unsigned short Ws[2][96][68];    // [buf][o][k]
    __shared__ float sc_s[HID], sh_s[HID];

    const int t = threadIdx.x;
    const int b = blockIdx.y;
    const int n0 = blockIdx.x * 64;
    const int wave = t >> 6, lane = t & 63;
    const int lm = lane & 15, g = lane >> 4;
    const int wo = wave >> 2, wn = wave & 3;
    const int nB = wn * 16 + lm;

    if (t < HID) { sc_s[t] = scale[t]; sh_s[t] = shift[t]; }

    f32x4 acc[3];
#pragma unroll
    for (int mt = 0; mt < 3; ++mt) acc[mt] = (f32x4){0.f, 0.f, 0.f, 0.f};

    const float* xbase = x + (size_t)b * CC * NPIX + n0;

    // --- staging geometry (chunk-invariant: c0 is a multiple of 64) ---
    // instr j in {0,1}: c_local = wave*8 + j*4 + g ; slot = lm*4 ^ X(c_local)
    // X(c) = ((c>>2)&3)*8  (32B-granular XOR, preserves 16B load granule)
    const int cl_0 = wave * 8 + g;
    const int cl_1 = wave * 8 + 4 + g;
    const size_t soff0 = (size_t)cl_0 * NPIX + ((lm * 4) ^ (((cl_0 >> 2) & 3) * 8));
    const size_t soff1 = (size_t)cl_1 * NPIX + ((lm * 4) ^ (((cl_1 >> 2) & 3) * 8));
    const int ldst0 = (wave * 8) * 64;          // wave-uniform LDS float index
    const int ldst1 = (wave * 8 + 4) * 64;

    // fragment-read swizzled column slots (per lane, per j-class)
    const int sA = nB ^ (((2 * g) & 3) * 8);        // rows j=0..3 of a k8-run
    const int sB = nB ^ (((2 * g + 1) & 3) * 8);    // rows j=4..7

#define ISSUE_X(buf, c0next) do {                                             \
    __builtin_amdgcn_global_load_lds(                                         \
        (gas_p)(xbase + (size_t)(c0next) * NPIX + soff0),                     \
        (las_p)(&Xs[buf][ldst0]), 16, 0, 0);                                  \
    __builtin_amdgcn_global_load_lds(                                         \
        (gas_p)(xbase + (size_t)(c0next) * NPIX + soff1),                     \
        (las_p)(&Xs[buf][ldst1]), 16, 0, 0);                                  \
    } while (0)

#define LOADW(c0n) do {                                                       \
    wr0 = *reinterpret_cast<const uint4*>(                                    \
        w1b + (size_t)(t >> 3) * CC + (c0n) + (t & 7) * 8);                   \
    if (t < 256)                                                              \
        wr1 = *reinterpret_cast<const uint4*>(                                \
            w1b + (size_t)((512 + t) >> 3) * CC + (c0n) + (t & 7) * 8);       \
    } while (0)

#define WRITEW(buf) do {                                                      \
    *reinterpret_cast<uint4*>(&Ws[buf][t >> 3][(t & 7) * 8]) = wr0;           \
    if (t < 256)                                                              \
        *reinterpret_cast<uint4*>(&Ws[buf][(512 + t) >> 3][(t & 7) * 8]) = wr1;\
    } while (0)

#define COMPUTE(buf) do {                                                     \
    const float* Xc = Xs[buf];                                                \
    _Pragma("unroll")                                                         \
    for (int h = 0; h < 2; ++h) {                                             \
        float f0 = Xc[(h * 32 + g * 8 + 0) * 64 + sA];                        \
        float f1 = Xc[(h * 32 + g * 8 + 1) * 64 + sA];                        \
        float f2 = Xc[(h * 32 + g * 8 + 2) * 64 + sA];                        \
        float f3 = Xc[(h * 32 + g * 8 + 3) * 64 + sA];                        \
        float f4 = Xc[(h * 32 + g * 8 + 4) * 64 + sB];                        \
        float f5 = Xc[(h * 32 + g * 8 + 5) * 64 + sB];                        \
        float f6 = Xc[(h * 32 + g * 8 + 6) * 64 + sB];                        \
        float f7 = Xc[(h * 32 + g * 8 + 7) * 64 + sB];                        \
        uint4 bu;                                                             \
        bu.x = pack2(f0, f1); bu.y = pack2(f2, f3);                           \
        bu.z = pack2(f4, f5); bu.w = pack2(f6, f7);                           \
        bf16x8 bfr = __builtin_bit_cast(bf16x8, bu);                          \
        _Pragma("unroll")                                                     \
        for (int mt = 0; mt < 3; ++mt) {                                      \
            uint4 au = *reinterpret_cast<const uint4*>(                       \
                &Ws[buf][wo * 48 + mt * 16 + lm][h * 32 + g * 8]);            \
            acc[mt] = __builtin_amdgcn_mfma_f32_16x16x32_bf16(                \
                __builtin_bit_cast(bf16x8, au), bfr, acc[mt], 0, 0, 0);       \
        }                                                                     \
    } } while (0)

    uint4 wr0, wr1;

    // ---- prologue: async-stage chunk 0 + W chunk 0 ----
    ISSUE_X(0, 0);
    LOADW(0);
    WRITEW(0);
    __syncthreads();   // drains gload queue -> chunk 0 resident

    int cur = 0;
#pragma unroll 1
    for (int c0 = 0; c0 < CC; c0 += 64) {
        const bool hasNext = (c0 + 64 < CC);
        if (hasNext) {
            ISSUE_X(cur ^ 1, c0 + 64);   // async; streams during compute
            LOADW(c0 + 64);
        }
        COMPUTE(cur);
        if (hasNext) WRITEW(cur ^ 1);
        __syncthreads();                 // drain = tail latency only
        cur ^= 1;
    }

    // epilogue: C/D col = lm (n), row = g*4 + r (o); BN + ReLU
#pragma unroll
    for (int mt = 0; mt < 3; ++mt) {
#pragma unroll
        for (int r = 0; r < 4; ++r) {
            int o = wo * 48 + mt * 16 + g * 4 + r;
            float v = fmaxf(acc[mt][r] * sc_s[o] + sh_s[o], 0.f);
            h_out[((size_t)b * HID + o) * NPIX + n0 + nB] = v;
        }
    }
#undef ISSUE_X
#undef LOADW
#undef WRITEW
#undef COMPUTE
}

// ---------------------------------------------------------------------------
// K2: 3x3 conv HID->1, SAME. grid (8 y-tiles of 4 rows, 32 b) = 256 blocks,
// 128 thr (1 px/thread). 16-channel LDS chunks with row halo.
// ---------------------------------------------------------------------------
__global__ __launch_bounds__(128) void k2_conv3x3(
    const float* __restrict__ h_in, const float* __restrict__ w2,
    const float* __restrict__ b2, float* __restrict__ score_out)
{
    __shared__ float hs[16][6][40];   // interior cols 4..35; halo cols 3 and 36
    __shared__ float w2s[HID * 9];

    const int t = threadIdx.x;
    const int ytile = blockIdx.x, b = blockIdx.y;
    const int y = t >> 5, xx = t & 31;
    const int Y = ytile * 4 + y;

    for (int i = t; i < HID * 9; i += 128) w2s[i] = w2[i];

    const float* hb = h_in + (size_t)b * HID * NPIX;
    float acc = 0.f;

    for (int c0 = 0; c0 < HID; c0 += 16) {
        __syncthreads();
        for (int i = t; i < 192; i += 128) {  // zero halo cols (3 and 36)
            int ch = i / 12, rr = (i % 12) >> 1, col = (i & 1) ? 36 : 3;
            hs[ch][rr][col] = 0.f;
        }
#pragma unroll
        for (int i = 0; i < 6; ++i) {
            int idx = t + i * 128;               // 0..767 float4 slots
            int ch = idx / 48, rem = idx % 48;
            int rr = rem >> 3, qq = rem & 7;
            int gy = ytile * 4 - 1 + rr;
            float4 v = (gy >= 0 && gy < 32)
                ? *reinterpret_cast<const float4*>(
                      hb + (size_t)(c0 + ch) * NPIX + gy * 32 + qq * 4)
                : (float4){0.f, 0.f, 0.f, 0.f};
            *reinterpret_cast<float4*>(&hs[ch][rr][4 + qq * 4]) = v;
        }
        __syncthreads();
#pragma unroll
        for (int ch = 0; ch < 16; ++ch) {
            float s = 0.f;
#pragma unroll
            for (int ky = 0; ky < 3; ++ky)
#pragma unroll
                for (int kx = 0; kx < 3; ++kx)
                    s += hs[ch][y + ky][3 + xx + kx] * w2s[(c0 + ch) * 9 + ky * 3 + kx];
            acc += s;
        }
    }
    score_out[b * NPIX + Y * 32 + xx] = acc + b2[0];
}

// ---------------------------------------------------------------------------
// K3: exact top-256 (radix select, first-index tie-break) + softmax ->
// dense weight[1024]. grid 32, 256 thr; elements register-resident (4/thr).
// ---------------------------------------------------------------------------
__global__ __launch_bounds__(256) void k3_topk_softmax(
    const float* __restrict__ score, float* __restrict__ weight)
{
    __shared__ unsigned hist[256];
    __shared__ unsigned wtot[4];
    __shared__ unsigned pcnt16[16];
    __shared__ float redf[4];
    __shared__ unsigned sh_bin, sh_rem;

    const int t = threadIdx.x, b = blockIdx.x;
    const int lane = t & 63, wv = t >> 6;

    float fvals[4];
    unsigned uvals[4];
#pragma unroll
    for (int i = 0; i < 4; ++i) {
        float f = score[b * NPIX + t + 256 * i];
        fvals[i] = f;
        unsigned u = __float_as_uint(f);
        uvals[i] = (u & 0x80000000u) ? ~u : (u | 0x80000000u);
    }

    unsigned prefix = 0, rem = KSEL;
    for (int p = 3; p >= 0; --p) {
        hist[t] = 0;
        __syncthreads();
        const int sh_hi = (p + 1) * 8;
#pragma unroll
        for (int i = 0; i < 4; ++i) {
            unsigned u = uvals[i];
            bool match = (p == 3) || ((u >> sh_hi) == (prefix >> sh_hi));
            if (match) atomicAdd(&hist[(u >> (p * 8)) & 0xffu], 1u);
        }
        __syncthreads();
        unsigned own = hist[t];
        unsigned val = own;
#pragma unroll
        for (int off = 1; off <= 32; off <<= 1) {
            unsigned o2 = __shfl_down(val, off);
            if (lane + off < 64) val += o2;
        }
        if (lane == 0) wtot[wv] = val;
        __syncthreads();
        unsigned suff = val;
        for (int w = wv + 1; w < 4; ++w) suff += wtot[w];
        unsigned nexts = suff - own;        // count with bin > t
        if (suff >= rem && nexts < rem) { sh_bin = (unsigned)t; sh_rem = rem - nexts; }
        __syncthreads();
        prefix |= (sh_bin << (p * 8));
        rem = sh_rem;
        __syncthreads();
    }
    const unsigned T = prefix, need = rem;

    float m = -INFINITY;
#pragma unroll
    for (int i = 0; i < 4; ++i) m = fmaxf(m, fvals[i]);
#pragma unroll
    for (int off = 32; off >= 1; off >>= 1) m = fmaxf(m, __shfl_xor(m, off));
    if (lane == 0) redf[wv] = m;
    __syncthreads();
    m = fmaxf(fmaxf(redf[0], redf[1]), fmaxf(redf[2], redf[3]));

    unsigned lp[4]; bool eqf[4], gtf[4];
    unsigned long long lmask = (1ULL << lane) - 1ULL;
#pragma unroll
    for (int i = 0; i < 4; ++i) {
        bool eq = (uvals[i] == T);
        eqf[i] = eq; gtf[i] = (uvals[i] > T);
        unsigned long long mk = __ballot(eq);
        lp[i] = (unsigned)__popcll(mk & lmask);
        if (lane == 0) pcnt16[i * 4 + wv] = (unsigned)__popcll(mk);
    }
    __syncthreads();
    unsigned cum = 0, baseArr[4];
#pragma unroll
    for (int ii = 0; ii < 4; ++ii) {
        unsigned b0 = cum;
        for (int w = 0; w < wv; ++w) b0 += pcnt16[ii * 4 + w];
        baseArr[ii] = b0;
        for (int w = 0; w < 4; ++w) cum += pcnt16[ii * 4 + w];
    }
    float evals[4], sumExp = 0.f;
#pragma unroll
    for (int i = 0; i < 4; ++i) {
        bool sel = gtf[i] || (eqf[i] && (baseArr[i] + lp[i]) < need);
        float e = sel ? expf(fvals[i] - m) : 0.f;
        evals[i] = e;
        sumExp += e;
    }
#pragma unroll
    for (int off = 32; off >= 1; off >>= 1) sumExp += __shfl_xor(sumExp, off);
    if (lane == 0) redf[wv] = sumExp;
    __syncthreads();
    float inv = 1.0f / (redf[0] + redf[1] + redf[2] + redf[3]);
#pragma unroll
    for (int i = 0; i < 4; ++i)
        weight[b * NPIX + i * 256 + t] = evals[i] * inv;
}

// ---------------------------------------------------------------------------
// K4: v[b,c] = sum_n x[b,c,n]*weight[b,n]. grid 32*192, 4 waves, 1 c/wave.
// ---------------------------------------------------------------------------
__global__ __launch_bounds__(256) void k4_weighted_sum(
    const float* __restrict__ x, const float* __restrict__ weight,
    float* __restrict__ v)
{
    __shared__ float wsm[NPIX];
    const int t = threadIdx.x;
    const int b = blockIdx.x / 192, cg = blockIdx.x % 192;

    *reinterpret_cast<float4*>(&wsm[t * 4]) =
        *reinterpret_cast<const float4*>(&weight[b * NPIX + t * 4]);
    __syncthreads();

    const int lane = t & 63, wvv = t >> 6;
    const int c = cg * 4 + wvv;
    const float* xr = x + ((size_t)b * CC + c) * NPIX;

    float acc = 0.f;
#pragma unroll
    for (int j = 0; j < 4; ++j) {
        int off = j * 256 + lane * 4;
        float4 xv = *reinterpret_cast<const float4*>(xr + off);
        float4 wv4 = *reinterpret_cast<const float4*>(&wsm[off]);
        acc += xv.x * wv4.x + xv.y * wv4.y + xv.z * wv4.z + xv.w * wv4.w;
    }
#pragma unroll
    for (int off = 32; off >= 1; off >>= 1) acc += __shfl_xor(acc, off);
    if (lane == 0) v[(size_t)b * CC + c] = acc;
}

// ---------------------------------------------------------------------------
extern "C" void kernel_launch(void* const* d_in, const int* in_sizes, int n_in,
                              void* d_out, int out_size, void* d_ws, size_t ws_size,
                              hipStream_t stream)
{
    const float* x     = (const float*)d_in[0];
    const float* w1    = (const float*)d_in[1];
    const float* gamma = (const float*)d_in[2];
    const float* beta  = (const float*)d_in[3];
    const float* mean  = (const float*)d_in[4];
    const float* var   = (const float*)d_in[5];
    const float* w2    = (const float*)d_in[6];
    const float* b2    = (const float*)d_in[7];

    float* out   = (float*)d_out;
    float* vout  = out;                  // [32,768]
    float* score = out + BB * CC;        // [32,1024]

    float* h       = (float*)d_ws;                                // 32*96*1024 f32
    float* weight  = h + (size_t)BB * HID * NPIX;                 // 32*1024 f32
    unsigned short* w1b = (unsigned short*)(weight + BB * NPIX);  // 96*768 bf16
    float* scale   = (float*)(w1b + HID * CC);                    // 96
    float* shift   = scale + HID;                                 // 96

    k0_prep<<<73, 256, 0, stream>>>(w1, gamma, beta, mean, var, w1b, scale, shift);
    k1_gemm_mfma<<<dim3(16, BB), 512, 0, stream>>>(x, w1b, scale, shift, h);
    k2_conv3x3<<<dim3(8, BB), 128, 0, stream>>>(h, w2, b2, score);
    k3_topk_softmax<<<BB, 256, 0, stream>>>(score, weight);
    k4_weighted_sum<<<BB * (CC / 4), 256, 0, stream>>>(x, weight, vout);
}